// Round 2
// baseline (283.009 us; speedup 1.0000x reference)
//
#include <hip/hip_runtime.h>
#include <hip/hip_bf16.h>

typedef __attribute__((ext_vector_type(8))) short bfx8;
typedef __attribute__((ext_vector_type(4))) float fx4;
typedef __attribute__((ext_vector_type(4))) unsigned short usx4;

#define ATT_SCALE 0.125f

__device__ __forceinline__ unsigned short f2bf(float f) {
  union { float f; unsigned int u; } a; a.f = f;
  unsigned int u = a.u;
  unsigned int r = (u + 0x7fffu + ((u >> 16) & 1u)) >> 16;
  return (unsigned short)r;
}

__device__ __forceinline__ float bf2f(unsigned short u) {
  union { unsigned int v; float f; } t; t.v = ((unsigned int)u) << 16;
  return t.f;
}

__device__ __forceinline__ void async16(const void* g, void* l) {
  __builtin_amdgcn_global_load_lds(
      (const __attribute__((address_space(1))) void*)g,
      (__attribute__((address_space(3))) void*)l, 16, 0, 0);
}

// f32 [R][1024] -> bf16 [R][2048] = [hi | lo]; one block per row
__global__ __launch_bounds__(256)
void cvtsplit(const float* __restrict__ s, unsigned short* __restrict__ d) {
  const int row = blockIdx.x;
  const int col = threadIdx.x * 4;
  fx4 v = *(const fx4*)(s + (size_t)row * 1024 + col);
  usx4 hi, lo;
#pragma unroll
  for (int j = 0; j < 4; ++j) {
    hi[j] = f2bf(v[j]);
    lo[j] = f2bf(v[j] - bf2f(hi[j]));
  }
  *(usx4*)(d + (size_t)row * 2048 + col) = hi;
  *(usx4*)(d + (size_t)row * 2048 + 1024 + col) = lo;
}

// plain f32 -> bf16, 1024 elements per block
__global__ __launch_bounds__(256)
void cvtbf(const float* __restrict__ s, unsigned short* __restrict__ d) {
  int i = (blockIdx.x * 256 + threadIdx.x) * 4;
  fx4 v = *(const fx4*)(s + i);
  usx4 o;
  o[0] = f2bf(v[0]); o[1] = f2bf(v[1]); o[2] = f2bf(v[2]); o[3] = f2bf(v[3]);
  *(usx4*)(d + i) = o;
}

// QKV projection, split-precision: A=h2 [4096][2048]=[h_hi|h_lo], W=[w_hi|w_lo] [1024][2048].
// Virtual K=3072: kt<16: hi*hi ; 16..31: lo*hi ; 32..47: hi*lo.
// sel = (by>>3)+sel_base: 0=Q (hi/lo out), 1=K (hi/lo out), 2=V (write V^T bf16).
__global__ __launch_bounds__(256, 2)
void gemm_qkv(const unsigned short* __restrict__ A,
              const unsigned short* __restrict__ Wq,
              const unsigned short* __restrict__ Wk,
              const unsigned short* __restrict__ Wv,
              unsigned short* __restrict__ Qh, unsigned short* __restrict__ Ql,
              unsigned short* __restrict__ Kh, unsigned short* __restrict__ Kl,
              unsigned short* __restrict__ Vt, int sel_base) {
  __shared__ unsigned short As[128 * 64];
  __shared__ unsigned short Bs[128 * 64];
  const int tid = threadIdx.x;
  const int w = tid >> 6, ln = tid & 63;
  const int mt = blockIdx.x;
  const int by = blockIdx.y;
  const int sel = (by >> 3) + sel_base;
  const int nt = by & 7;
  const unsigned short* W = (sel == 0) ? Wq : ((sel == 1) ? Wk : Wv);
  const int m0 = mt * 128, n0 = nt * 128;
  const int wr = w >> 1, wc = w & 1;
  fx4 acc[4][4] = {};

  const int lr = ln >> 3;
  const int scg = (ln & 7) ^ lr;
  const unsigned short* Asrc = A + (size_t)(m0 + w * 32 + lr) * 2048 + scg * 8;
  const unsigned short* Bsrc = W + (size_t)(n0 + w * 32 + lr) * 2048 + scg * 8;

  for (int kt = 0; kt < 48; ++kt) {
    const int ka = (kt < 32 ? kt : kt - 32) * 64;
    const int kw_ = (kt < 16 ? kt : kt - 16) * 64;
    __syncthreads();
#pragma unroll
    for (int i = 0; i < 4; ++i) {
      async16(Asrc + (size_t)i * 8 * 2048 + ka, &As[(w * 32 + i * 8) * 64]);
      async16(Bsrc + (size_t)i * 8 * 2048 + kw_, &Bs[(w * 32 + i * 8) * 64]);
    }
    __syncthreads();
#pragma unroll
    for (int kk = 0; kk < 2; ++kk) {
      const int kg = kk * 4 + (ln >> 4);
      bfx8 af[4], bfr[4];
#pragma unroll
      for (int mi = 0; mi < 4; ++mi) {
        int row = wr * 64 + mi * 16 + (ln & 15);
        af[mi] = *(const bfx8*)&As[row * 64 + ((kg ^ (row & 7)) * 8)];
      }
#pragma unroll
      for (int ni = 0; ni < 4; ++ni) {
        int row = wc * 64 + ni * 16 + (ln & 15);
        bfr[ni] = *(const bfx8*)&Bs[row * 64 + ((kg ^ (row & 7)) * 8)];
      }
#pragma unroll
      for (int mi = 0; mi < 4; ++mi)
#pragma unroll
        for (int ni = 0; ni < 4; ++ni)
          acc[mi][ni] = __builtin_amdgcn_mfma_f32_16x16x32_bf16(af[mi], bfr[ni], acc[mi][ni], 0, 0, 0);
    }
  }
  const int cb = n0 + wc * 64 + (ln & 15);
  const int rb = m0 + wr * 64 + ((ln >> 4) << 2);
  if (sel < 2) {
    unsigned short* Oh = sel ? Kh : Qh;
    unsigned short* Ol = sel ? Kl : Ql;
#pragma unroll
    for (int mi = 0; mi < 4; ++mi)
#pragma unroll
      for (int ni = 0; ni < 4; ++ni)
#pragma unroll
        for (int j = 0; j < 4; ++j) {
          int r = rb + mi * 16 + j;
          int c = cb + ni * 16;
          float v = acc[mi][ni][j];
          unsigned short hi = f2bf(v);
          unsigned short lo = f2bf(v - bf2f(hi));
          Oh[(size_t)r * 1024 + c] = hi;
          Ol[(size_t)r * 1024 + c] = lo;
        }
  } else {
    // V^T: Vt[((b*16+h)*64+d)][s], 4 consecutive s per lane -> usx4
#pragma unroll
    for (int mi = 0; mi < 4; ++mi)
#pragma unroll
      for (int ni = 0; ni < 4; ++ni) {
        int s0 = rb + mi * 16;
        int c = cb + ni * 16;
        int bI = s0 >> 11, s = s0 & 2047;
        int hh = c >> 6, dd = c & 63;
        usx4 pk;
#pragma unroll
        for (int j = 0; j < 4; ++j) pk[j] = f2bf(acc[mi][ni][j]);
        *(usx4*)&Vt[((size_t)(bI * 16 + hh) * 64 + dd) * 2048 + s] = pk;
      }
  }
}

// O-projection: C = A[4096][1024] * W^T, f32 out
__global__ __launch_bounds__(256, 2)
void gemm_o(const unsigned short* __restrict__ A,
            const unsigned short* __restrict__ W,
            float* __restrict__ O) {
  __shared__ unsigned short As[128 * 64];
  __shared__ unsigned short Bs[128 * 64];
  const int tid = threadIdx.x;
  const int w = tid >> 6, ln = tid & 63;
  const int mt = blockIdx.x, nt = blockIdx.y;
  const int m0 = mt * 128, n0 = nt * 128;
  const int wr = w >> 1, wc = w & 1;
  fx4 acc[4][4] = {};
  const int lr = ln >> 3;
  const int scg = (ln & 7) ^ lr;
  const unsigned short* Asrc = A + (size_t)(m0 + w * 32 + lr) * 1024 + scg * 8;
  const unsigned short* Bsrc = W + (size_t)(n0 + w * 32 + lr) * 1024 + scg * 8;

  for (int kt = 0; kt < 16; ++kt) {
    const int k0 = kt * 64;
    __syncthreads();
#pragma unroll
    for (int i = 0; i < 4; ++i) {
      async16(Asrc + (size_t)i * 8 * 1024 + k0, &As[(w * 32 + i * 8) * 64]);
      async16(Bsrc + (size_t)i * 8 * 1024 + k0, &Bs[(w * 32 + i * 8) * 64]);
    }
    __syncthreads();
#pragma unroll
    for (int kk = 0; kk < 2; ++kk) {
      const int kg = kk * 4 + (ln >> 4);
      bfx8 af[4], bfr[4];
#pragma unroll
      for (int mi = 0; mi < 4; ++mi) {
        int row = wr * 64 + mi * 16 + (ln & 15);
        af[mi] = *(const bfx8*)&As[row * 64 + ((kg ^ (row & 7)) * 8)];
      }
#pragma unroll
      for (int ni = 0; ni < 4; ++ni) {
        int row = wc * 64 + ni * 16 + (ln & 15);
        bfr[ni] = *(const bfx8*)&Bs[row * 64 + ((kg ^ (row & 7)) * 8)];
      }
#pragma unroll
      for (int mi = 0; mi < 4; ++mi)
#pragma unroll
        for (int ni = 0; ni < 4; ++ni)
          acc[mi][ni] = __builtin_amdgcn_mfma_f32_16x16x32_bf16(af[mi], bfr[ni], acc[mi][ni], 0, 0, 0);
    }
  }
  const int cb = n0 + wc * 64 + (ln & 15);
  const int rb = m0 + wr * 64 + ((ln >> 4) << 2);
#pragma unroll
  for (int mi = 0; mi < 4; ++mi)
#pragma unroll
    for (int ni = 0; ni < 4; ++ni)
#pragma unroll
      for (int j = 0; j < 4; ++j)
        O[(size_t)(rb + mi * 16 + j) * 1024 + cb + ni * 16] = acc[mi][ni][j];
}

// Flash attention, 3-term split QK^T. block=(qt,h,b); 4 waves x 16 q-rows; K-tile=128.
__global__ __launch_bounds__(256, 2)
void attn_fwd(const unsigned short* __restrict__ Qhp,
              const unsigned short* __restrict__ Qlp,
              const unsigned short* __restrict__ Khp,
              const unsigned short* __restrict__ Klp,
              const unsigned short* __restrict__ Vt,
              const int* __restrict__ mask,
              unsigned short* __restrict__ Ov) {
  __shared__ unsigned short Ksh[128 * 64];
  __shared__ unsigned short Ksl[128 * 64];
  __shared__ unsigned short Vs[64 * 128];
  __shared__ unsigned short Ps[64 * 128];
  __shared__ float mf[128];
  const int tid = threadIdx.x;
  const int w = tid >> 6, ln = tid & 63;
  const int qt = blockIdx.x, h = blockIdx.y, b = blockIdx.z;
  const int q0 = qt * 64;

  bfx8 qfh[2], qfl[2];
  {
    int q = q0 + w * 16 + (ln & 15);
    size_t off = (size_t)(b * 2048 + q) * 1024 + h * 64 + ((ln >> 4) * 8);
    qfh[0] = *(const bfx8*)(Qhp + off);
    qfh[1] = *(const bfx8*)(Qhp + off + 32);
    qfl[0] = *(const bfx8*)(Qlp + off);
    qfl[1] = *(const bfx8*)(Qlp + off + 32);
  }
  fx4 o[4] = {};
  float mrow[4] = {-INFINITY, -INFINITY, -INFINITY, -INFINITY};
  float lrow[4] = {0.f, 0.f, 0.f, 0.f};

  const int lr = ln >> 3;
  const int scg = (ln & 7) ^ lr;
  const size_t koff = (size_t)(b * 2048 + w * 32 + lr) * 1024 + h * 64 + scg * 8;
  const unsigned short* Ksrch = Khp + koff;
  const unsigned short* Ksrcl = Klp + koff;
  const int vr = ln >> 4;
  const int vcg = ln & 15;
  const unsigned short* Vbase = Vt + (size_t)(b * 16 + h) * 64 * 2048;

  for (int kt = 0; kt < 16; ++kt) {
    __syncthreads();
#pragma unroll
    for (int i = 0; i < 4; ++i) {
      async16(Ksrch + (size_t)(kt * 128 + i * 8) * 1024, &Ksh[(w * 32 + i * 8) * 64]);
      async16(Ksrcl + (size_t)(kt * 128 + i * 8) * 1024, &Ksl[(w * 32 + i * 8) * 64]);
    }
#pragma unroll
    for (int i = 0; i < 4; ++i) {
      int d = w * 16 + i * 4 + vr;
      async16(Vbase + (size_t)d * 2048 + kt * 128 + ((vcg ^ (d & 7)) * 8),
              &Vs[(w * 16 + i * 4) * 128]);
    }
    if (tid < 128)
      mf[tid] = (mask[b * 2048 + kt * 128 + tid] == 0) ? -1e30f : 0.0f;
    __syncthreads();

    // S = (Q K^T) * scale + mask  (3-term hi/lo)
    fx4 s[8];
#pragma unroll
    for (int ni = 0; ni < 8; ++ni) {
      fx4 z = {};
#pragma unroll
      for (int kk = 0; kk < 2; ++kk) {
        int row = ni * 16 + (ln & 15);
        int kg = kk * 4 + (ln >> 4);
        int off = row * 64 + ((kg ^ (row & 7)) * 8);
        bfx8 khf = *(const bfx8*)&Ksh[off];
        bfx8 klf = *(const bfx8*)&Ksl[off];
        z = __builtin_amdgcn_mfma_f32_16x16x32_bf16(qfh[kk], khf, z, 0, 0, 0);
        z = __builtin_amdgcn_mfma_f32_16x16x32_bf16(qfl[kk], khf, z, 0, 0, 0);
        z = __builtin_amdgcn_mfma_f32_16x16x32_bf16(qfh[kk], klf, z, 0, 0, 0);
      }
      s[ni] = z;
    }
    // online softmax (rows = (ln>>4)*4+j, cols over 16 lanes x 8 frags)
    const int colb = ln & 15;
    float tm[4] = {-INFINITY, -INFINITY, -INFINITY, -INFINITY};
#pragma unroll
    for (int ni = 0; ni < 8; ++ni) {
      float mc = mf[ni * 16 + colb];
#pragma unroll
      for (int j = 0; j < 4; ++j) {
        float v = s[ni][j] * ATT_SCALE + mc;
        s[ni][j] = v;
        tm[j] = fmaxf(tm[j], v);
      }
    }
#pragma unroll
    for (int mm = 1; mm < 16; mm <<= 1)
#pragma unroll
      for (int j = 0; j < 4; ++j)
        tm[j] = fmaxf(tm[j], __shfl_xor(tm[j], mm));
    float fac[4], psum[4];
#pragma unroll
    for (int j = 0; j < 4; ++j) {
      float mn = fmaxf(mrow[j], tm[j]);
      fac[j] = __expf(mrow[j] - mn);
      mrow[j] = mn;
      psum[j] = 0.f;
    }
    const int prow0 = w * 16 + ((ln >> 4) << 2);
#pragma unroll
    for (int ni = 0; ni < 8; ++ni) {
      int col = ni * 16 + colb;
      int cg = col >> 3, coff = col & 7;
#pragma unroll
      for (int j = 0; j < 4; ++j) {
        float p = __expf(s[ni][j] - mrow[j]);
        psum[j] += p;
        int row = prow0 + j;
        Ps[row * 128 + ((cg ^ (row & 7)) * 8) + coff] = f2bf(p);
      }
    }
#pragma unroll
    for (int mm = 1; mm < 16; mm <<= 1)
#pragma unroll
      for (int j = 0; j < 4; ++j)
        psum[j] += __shfl_xor(psum[j], mm);
#pragma unroll
    for (int j = 0; j < 4; ++j)
      lrow[j] = lrow[j] * fac[j] + psum[j];
#pragma unroll
    for (int di = 0; di < 4; ++di)
#pragma unroll
      for (int j = 0; j < 4; ++j)
        o[di][j] *= fac[j];
    // O += P V
#pragma unroll
    for (int kk = 0; kk < 4; ++kk) {
      int prow = w * 16 + (ln & 15);
      int pg = kk * 4 + (ln >> 4);
      bfx8 pa = *(const bfx8*)&Ps[prow * 128 + ((pg ^ (prow & 7)) * 8)];
#pragma unroll
      for (int di = 0; di < 4; ++di) {
        int vrow = di * 16 + (ln & 15);
        bfx8 vb = *(const bfx8*)&Vs[vrow * 128 + ((pg ^ (vrow & 7)) * 8)];
        o[di] = __builtin_amdgcn_mfma_f32_16x16x32_bf16(pa, vb, o[di], 0, 0, 0);
      }
    }
  }
#pragma unroll
  for (int di = 0; di < 4; ++di)
#pragma unroll
    for (int j = 0; j < 4; ++j) {
      int sq_ = q0 + w * 16 + ((ln >> 4) << 2) + j;
      float v = o[di][j] / lrow[j];
      Ov[(size_t)(b * 2048 + sq_) * 1024 + h * 64 + di * 16 + (ln & 15)] = f2bf(v);
    }
}

// out = LayerNorm(h + attn_out) * g + b ; one block per row
__global__ __launch_bounds__(256)
void lnk(const float* __restrict__ h, const float* __restrict__ ao,
         const float* __restrict__ g, const float* __restrict__ bb,
         float* __restrict__ out) {
  const int row = blockIdx.x;
  const int tid = threadIdx.x;
  const size_t base = (size_t)row * 1024 + tid * 4;
  fx4 x = *(const fx4*)(h + base);
  fx4 a = *(const fx4*)(ao + base);
  x = x + a;
  float s = x[0] + x[1] + x[2] + x[3];
  float q = x[0] * x[0] + x[1] * x[1] + x[2] * x[2] + x[3] * x[3];
#pragma unroll
  for (int mm = 1; mm < 64; mm <<= 1) {
    s += __shfl_xor(s, mm);
    q += __shfl_xor(q, mm);
  }
  __shared__ float rs[4], rq[4];
  if ((tid & 63) == 0) { rs[tid >> 6] = s; rq[tid >> 6] = q; }
  __syncthreads();
  s = rs[0] + rs[1] + rs[2] + rs[3];
  q = rq[0] + rq[1] + rq[2] + rq[3];
  float mu = s * (1.0f / 1024.0f);
  float var = q * (1.0f / 1024.0f) - mu * mu;
  float rstd = rsqrtf(var + 1e-5f);
  fx4 gg = *(const fx4*)(g + tid * 4);
  fx4 bv = *(const fx4*)(bb + tid * 4);
  fx4 ov;
#pragma unroll
  for (int k = 0; k < 4; ++k) ov[k] = (x[k] - mu) * rstd * gg[k] + bv[k];
  *(fx4*)(out + base) = ov;
}

extern "C" void kernel_launch(void* const* d_in, const int* in_sizes, int n_in,
                              void* d_out, int out_size, void* d_ws, size_t ws_size,
                              hipStream_t stream) {
  const float* h = (const float*)d_in[0];
  const int* msk = (const int*)d_in[1];
  const float* qw = (const float*)d_in[2];
  const float* kw = (const float*)d_in[3];
  const float* vw = (const float*)d_in[4];
  const float* ow = (const float*)d_in[5];
  const float* lng = (const float*)d_in[6];
  const float* lnb = (const float*)d_in[7];
  float* out = (float*)d_out;
  char* ws = (char*)d_ws;

  const size_t MB = 1u << 20;
  unsigned short* h2  = (unsigned short*)(ws + 0 * MB);   // 16 MB [hi|lo]
  unsigned short* w2q = (unsigned short*)(ws + 16 * MB);  // 4 MB
  unsigned short* w2k = (unsigned short*)(ws + 20 * MB);  // 4 MB
  unsigned short* w2v = (unsigned short*)(ws + 24 * MB);  // 4 MB (dead after V gemm)
  unsigned short* Qh  = (unsigned short*)(ws + 24 * MB);  // 8 MB (over w2v, written later)
  unsigned short* Ql  = (unsigned short*)(ws + 32 * MB);  // 8 MB
  unsigned short* Kh  = (unsigned short*)(ws + 40 * MB);  // 8 MB
  unsigned short* Kl  = (unsigned short*)(ws + 48 * MB);  // 8 MB
  unsigned short* Vtb = (unsigned short*)(ws + 56 * MB);  // 8 MB
  unsigned short* Av  = (unsigned short*)(ws + 0 * MB);   // 8 MB (over h2, dead)
  unsigned short* wo  = (unsigned short*)(ws + 8 * MB);   // 2 MB (over h2, dead)
  float* Ao = (float*)(ws + 10 * MB);                     // 16 MB (over h2/w2q/w2k/Qh-head, dead)

  cvtsplit<<<dim3(4096), 256, 0, stream>>>(h, h2);
  cvtsplit<<<dim3(1024), 256, 0, stream>>>(qw, w2q);
  cvtsplit<<<dim3(1024), 256, 0, stream>>>(kw, w2k);
  cvtsplit<<<dim3(1024), 256, 0, stream>>>(vw, w2v);

  // V first (reads w2v), then Q/K (overwrites w2v region with Qh)
  gemm_qkv<<<dim3(32, 8), 256, 0, stream>>>(h2, w2q, w2k, w2v, Qh, Ql, Kh, Kl, Vtb, 2);
  gemm_qkv<<<dim3(32, 16), 256, 0, stream>>>(h2, w2q, w2k, w2v, Qh, Ql, Kh, Kl, Vtb, 0);

  attn_fwd<<<dim3(32, 16, 2), 256, 0, stream>>>(Qh, Ql, Kh, Kl, Vtb, msk, Av);

  cvtbf<<<dim3(1024), 256, 0, stream>>>(ow, wo);
  gemm_o<<<dim3(32, 8), 256, 0, stream>>>(Av, wo, Ao);
  lnk<<<dim3(4096), 256, 0, stream>>>(h, Ao, lng, lnb, out);
}

// Round 3
// 236.764 us; speedup vs baseline: 1.1953x; 1.1953x over previous
//
#include <hip/hip_runtime.h>
#include <hip/hip_bf16.h>

typedef __attribute__((ext_vector_type(8))) short bfx8;
typedef __attribute__((ext_vector_type(4))) float fx4;
typedef __attribute__((ext_vector_type(4))) unsigned short usx4;

#define ATT_SCALE 0.125f

__device__ __forceinline__ unsigned short f2bf(float f) {
  union { float f; unsigned int u; } a; a.f = f;
  unsigned int u = a.u;
  unsigned int r = (u + 0x7fffu + ((u >> 16) & 1u)) >> 16;
  return (unsigned short)r;
}

__device__ __forceinline__ float bf2f(unsigned short u) {
  union { unsigned int v; float f; } t; t.v = ((unsigned int)u) << 16;
  return t.f;
}

__device__ __forceinline__ unsigned int pkbf(float a, float b) {
  return (unsigned int)f2bf(a) | ((unsigned int)f2bf(b) << 16);
}

__device__ __forceinline__ void async16(const void* g, void* l) {
  __builtin_amdgcn_global_load_lds(
      (const __attribute__((address_space(1))) void*)g,
      (__attribute__((address_space(3))) void*)l, 16, 0, 0);
}

// f32 [R][1024] -> bf16 [R][2048] = [hi | lo]; one block per row
__global__ __launch_bounds__(256)
void cvtsplit(const float* __restrict__ s, unsigned short* __restrict__ d) {
  const int row = blockIdx.x;
  const int col = threadIdx.x * 4;
  fx4 v = *(const fx4*)(s + (size_t)row * 1024 + col);
  usx4 hi, lo;
#pragma unroll
  for (int j = 0; j < 4; ++j) {
    hi[j] = f2bf(v[j]);
    lo[j] = f2bf(v[j] - bf2f(hi[j]));
  }
  *(usx4*)(d + (size_t)row * 2048 + col) = hi;
  *(usx4*)(d + (size_t)row * 2048 + 1024 + col) = lo;
}

// plain f32 -> bf16, 1024 elements per block
__global__ __launch_bounds__(256)
void cvtbf(const float* __restrict__ s, unsigned short* __restrict__ d) {
  int i = (blockIdx.x * 256 + threadIdx.x) * 4;
  fx4 v = *(const fx4*)(s + i);
  usx4 o;
  o[0] = f2bf(v[0]); o[1] = f2bf(v[1]); o[2] = f2bf(v[2]); o[3] = f2bf(v[3]);
  *(usx4*)(d + i) = o;
}

// QKV projection, split-precision: A=h2 [4096][2048]=[h_hi|h_lo], W=[w_hi|w_lo] [1024][2048].
// Virtual K (nkt=48): kt<16: hi*hi ; 16..31: lo*hi ; 32..47: hi*lo. nkt=16: hi*hi only.
// sel = (by>>3)+sel_base: 0=Q (hi/lo out), 1=K (hi/lo out), 2=V (write V^T bf16).
__global__ __launch_bounds__(256, 2)
void gemm_qkv(const unsigned short* __restrict__ A,
              const unsigned short* __restrict__ Wq,
              const unsigned short* __restrict__ Wk,
              const unsigned short* __restrict__ Wv,
              unsigned short* __restrict__ Qh, unsigned short* __restrict__ Ql,
              unsigned short* __restrict__ Kh, unsigned short* __restrict__ Kl,
              unsigned short* __restrict__ Vt, int sel_base, int nkt) {
  __shared__ unsigned short As[128 * 64];
  __shared__ unsigned short Bs[128 * 64];
  const int tid = threadIdx.x;
  const int w = tid >> 6, ln = tid & 63;
  const int mt = blockIdx.x;
  const int by = blockIdx.y;
  const int sel = (by >> 3) + sel_base;
  const int nt = by & 7;
  const unsigned short* W = (sel == 0) ? Wq : ((sel == 1) ? Wk : Wv);
  const int m0 = mt * 128, n0 = nt * 128;
  const int wr = w >> 1, wc = w & 1;
  fx4 acc[4][4] = {};

  const int lr = ln >> 3;
  const int scg = (ln & 7) ^ lr;
  const unsigned short* Asrc = A + (size_t)(m0 + w * 32 + lr) * 2048 + scg * 8;
  const unsigned short* Bsrc = W + (size_t)(n0 + w * 32 + lr) * 2048 + scg * 8;

  for (int kt = 0; kt < nkt; ++kt) {
    const int ka = (kt < 32 ? kt : kt - 32) * 64;
    const int kw_ = (kt < 16 ? kt : kt - 16) * 64;
    __syncthreads();
#pragma unroll
    for (int i = 0; i < 4; ++i) {
      async16(Asrc + (size_t)i * 8 * 2048 + ka, &As[(w * 32 + i * 8) * 64]);
      async16(Bsrc + (size_t)i * 8 * 2048 + kw_, &Bs[(w * 32 + i * 8) * 64]);
    }
    __syncthreads();
#pragma unroll
    for (int kk = 0; kk < 2; ++kk) {
      const int kg = kk * 4 + (ln >> 4);
      bfx8 af[4], bfr[4];
#pragma unroll
      for (int mi = 0; mi < 4; ++mi) {
        int row = wr * 64 + mi * 16 + (ln & 15);
        af[mi] = *(const bfx8*)&As[row * 64 + ((kg ^ (row & 7)) * 8)];
      }
#pragma unroll
      for (int ni = 0; ni < 4; ++ni) {
        int row = wc * 64 + ni * 16 + (ln & 15);
        bfr[ni] = *(const bfx8*)&Bs[row * 64 + ((kg ^ (row & 7)) * 8)];
      }
#pragma unroll
      for (int mi = 0; mi < 4; ++mi)
#pragma unroll
        for (int ni = 0; ni < 4; ++ni)
          acc[mi][ni] = __builtin_amdgcn_mfma_f32_16x16x32_bf16(af[mi], bfr[ni], acc[mi][ni], 0, 0, 0);
    }
  }
  const int cb = n0 + wc * 64 + (ln & 15);
  const int rb = m0 + wr * 64 + ((ln >> 4) << 2);
  if (sel < 2) {
    unsigned short* Oh = sel ? Kh : Qh;
    unsigned short* Ol = sel ? Kl : Ql;
#pragma unroll
    for (int mi = 0; mi < 4; ++mi)
#pragma unroll
      for (int ni = 0; ni < 4; ++ni)
#pragma unroll
        for (int j = 0; j < 4; ++j) {
          int r = rb + mi * 16 + j;
          int c = cb + ni * 16;
          float v = acc[mi][ni][j];
          unsigned short hi = f2bf(v);
          unsigned short lo = f2bf(v - bf2f(hi));
          Oh[(size_t)r * 1024 + c] = hi;
          Ol[(size_t)r * 1024 + c] = lo;
        }
  } else {
    // V^T: Vt[((b*16+h)*64+d)][s], 4 consecutive s per lane -> usx4
#pragma unroll
    for (int mi = 0; mi < 4; ++mi)
#pragma unroll
      for (int ni = 0; ni < 4; ++ni) {
        int s0 = rb + mi * 16;
        int c = cb + ni * 16;
        int bI = s0 >> 11, s = s0 & 2047;
        int hh = c >> 6, dd = c & 63;
        usx4 pk;
#pragma unroll
        for (int j = 0; j < 4; ++j) pk[j] = f2bf(acc[mi][ni][j]);
        *(usx4*)&Vt[((size_t)(bI * 16 + hh) * 64 + dd) * 2048 + s] = pk;
      }
  }
}

// O-projection: C = A[4096][1024] * W^T, f32 out
__global__ __launch_bounds__(256, 2)
void gemm_o(const unsigned short* __restrict__ A,
            const unsigned short* __restrict__ W,
            float* __restrict__ O) {
  __shared__ unsigned short As[128 * 64];
  __shared__ unsigned short Bs[128 * 64];
  const int tid = threadIdx.x;
  const int w = tid >> 6, ln = tid & 63;
  const int mt = blockIdx.x, nt = blockIdx.y;
  const int m0 = mt * 128, n0 = nt * 128;
  const int wr = w >> 1, wc = w & 1;
  fx4 acc[4][4] = {};
  const int lr = ln >> 3;
  const int scg = (ln & 7) ^ lr;
  const unsigned short* Asrc = A + (size_t)(m0 + w * 32 + lr) * 1024 + scg * 8;
  const unsigned short* Bsrc = W + (size_t)(n0 + w * 32 + lr) * 1024 + scg * 8;

  for (int kt = 0; kt < 16; ++kt) {
    const int k0 = kt * 64;
    __syncthreads();
#pragma unroll
    for (int i = 0; i < 4; ++i) {
      async16(Asrc + (size_t)i * 8 * 1024 + k0, &As[(w * 32 + i * 8) * 64]);
      async16(Bsrc + (size_t)i * 8 * 1024 + k0, &Bs[(w * 32 + i * 8) * 64]);
    }
    __syncthreads();
#pragma unroll
    for (int kk = 0; kk < 2; ++kk) {
      const int kg = kk * 4 + (ln >> 4);
      bfx8 af[4], bfr[4];
#pragma unroll
      for (int mi = 0; mi < 4; ++mi) {
        int row = wr * 64 + mi * 16 + (ln & 15);
        af[mi] = *(const bfx8*)&As[row * 64 + ((kg ^ (row & 7)) * 8)];
      }
#pragma unroll
      for (int ni = 0; ni < 4; ++ni) {
        int row = wc * 64 + ni * 16 + (ln & 15);
        bfr[ni] = *(const bfx8*)&Bs[row * 64 + ((kg ^ (row & 7)) * 8)];
      }
#pragma unroll
      for (int mi = 0; mi < 4; ++mi)
#pragma unroll
        for (int ni = 0; ni < 4; ++ni)
          acc[mi][ni] = __builtin_amdgcn_mfma_f32_16x16x32_bf16(af[mi], bfr[ni], acc[mi][ni], 0, 0, 0);
    }
  }
  const int cb = n0 + wc * 64 + (ln & 15);
  const int rb = m0 + wr * 64 + ((ln >> 4) << 2);
#pragma unroll
  for (int mi = 0; mi < 4; ++mi)
#pragma unroll
    for (int ni = 0; ni < 4; ++ni)
#pragma unroll
      for (int j = 0; j < 4; ++j)
        O[(size_t)(rb + mi * 16 + j) * 1024 + cb + ni * 16] = acc[mi][ni][j];
}

// Flash attention, swapped QK^T (scores come out as C[key][q], q = lane&15 -> softmax
// state is per-lane scalar, P transposed to A-frag in-register via shfl; no P LDS).
// block = (qt,h,b); 8 waves x 16 q-rows = 128 q-rows; K-tile = 128.
__global__ __launch_bounds__(512, 4)
void attn_fwd(const unsigned short* __restrict__ Qhp,
              const unsigned short* __restrict__ Qlp,
              const unsigned short* __restrict__ Khp,
              const unsigned short* __restrict__ Klp,
              const unsigned short* __restrict__ Vt,
              const int* __restrict__ mask,
              unsigned short* __restrict__ Ov) {
  __shared__ unsigned short Ksh[128 * 64];
  __shared__ unsigned short Ksl[128 * 64];
  __shared__ unsigned short Vs[64 * 128];
  __shared__ float mf[128];
  const int tid = threadIdx.x;
  const int w = tid >> 6, ln = tid & 63;
  const int qt = blockIdx.x, h = blockIdx.y, b = blockIdx.z;
  const int q0 = qt * 128;
  const int g = ln >> 4, qy = ln & 15;

  // Q as B-fragment: lane holds Q[q0 + w*16 + qy][dims kk*32 + g*8 + 0..7]
  bfx8 qfh[2], qfl[2];
  {
    int q = q0 + w * 16 + qy;
    size_t off = (size_t)(b * 2048 + q) * 1024 + h * 64 + g * 8;
    qfh[0] = *(const bfx8*)(Qhp + off);
    qfh[1] = *(const bfx8*)(Qhp + off + 32);
    qfl[0] = *(const bfx8*)(Qlp + off);
    qfl[1] = *(const bfx8*)(Qlp + off + 32);
  }
  fx4 o[4] = {};
  float mrow = -INFINITY, lrow = 0.f;

  const int lr = ln >> 3;
  const int scg = (ln & 7) ^ lr;
  const size_t koff = (size_t)(b * 2048 + w * 16 + lr) * 1024 + h * 64 + scg * 8;
  const unsigned short* Ksrch = Khp + koff;
  const unsigned short* Ksrcl = Klp + koff;
  const unsigned short* Vbase = Vt + (size_t)(b * 16 + h) * 64 * 2048;

  for (int kt = 0; kt < 16; ++kt) {
    __syncthreads();
#pragma unroll
    for (int i = 0; i < 2; ++i) {
      async16(Ksrch + (size_t)(kt * 128 + i * 8) * 1024, &Ksh[(w * 16 + i * 8) * 64]);
      async16(Ksrcl + (size_t)(kt * 128 + i * 8) * 1024, &Ksl[(w * 16 + i * 8) * 64]);
    }
#pragma unroll
    for (int i = 0; i < 2; ++i) {
      int d = w * 8 + i * 4 + g;
      async16(Vbase + (size_t)d * 2048 + kt * 128 + ((qy ^ (d & 7)) * 8),
              &Vs[(w * 8 + i * 4) * 128]);
    }
    if (tid < 128)
      mf[tid] = (mask[b * 2048 + kt * 128 + tid] == 0) ? -1e30f : 0.0f;
    __syncthreads();

    // S^T = K Q^T (3-term hi/lo): C[key = ni*16 + g*4 + j][q = qy]
    fx4 s[8];
#pragma unroll
    for (int ni = 0; ni < 8; ++ni) {
      fx4 z = {};
#pragma unroll
      for (int kk = 0; kk < 2; ++kk) {
        int row = ni * 16 + qy;
        int kg = kk * 4 + g;
        int off = row * 64 + ((kg ^ (row & 7)) * 8);
        bfx8 khf = *(const bfx8*)&Ksh[off];
        bfx8 klf = *(const bfx8*)&Ksl[off];
        z = __builtin_amdgcn_mfma_f32_16x16x32_bf16(khf, qfh[kk], z, 0, 0, 0);
        z = __builtin_amdgcn_mfma_f32_16x16x32_bf16(khf, qfl[kk], z, 0, 0, 0);
        z = __builtin_amdgcn_mfma_f32_16x16x32_bf16(klf, qfh[kk], z, 0, 0, 0);
      }
      s[ni] = z;
    }
    // scale + mask + per-q (lane-local) online softmax
    float tm = -INFINITY;
#pragma unroll
    for (int ni = 0; ni < 8; ++ni) {
      fx4 mfv = *(const fx4*)&mf[ni * 16 + g * 4];
#pragma unroll
      for (int j = 0; j < 4; ++j) {
        float v = s[ni][j] * ATT_SCALE + mfv[j];
        s[ni][j] = v;
        tm = fmaxf(tm, v);
      }
    }
    tm = fmaxf(tm, __shfl_xor(tm, 16));
    tm = fmaxf(tm, __shfl_xor(tm, 32));
    float mn = fmaxf(mrow, tm);
    float fac = __expf(mrow - mn);
    mrow = mn;
    float psum = 0.f;
    unsigned int wA[8], wB[8];
#pragma unroll
    for (int ni = 0; ni < 8; ++ni) {
      float p0 = __expf(s[ni][0] - mrow);
      float p1 = __expf(s[ni][1] - mrow);
      float p2 = __expf(s[ni][2] - mrow);
      float p3 = __expf(s[ni][3] - mrow);
      psum += (p0 + p1) + (p2 + p3);
      wA[ni] = pkbf(p0, p1);
      wB[ni] = pkbf(p2, p3);
    }
    psum += __shfl_xor(psum, 16);
    psum += __shfl_xor(psum, 32);
    lrow = lrow * fac + psum;
    // rescale o (o rows are q = g*4 + j; fac lives at lane q)
    float facj[4];
#pragma unroll
    for (int j = 0; j < 4; ++j) facj[j] = __shfl(fac, g * 4 + j);
#pragma unroll
    for (int di = 0; di < 4; ++di)
#pragma unroll
      for (int j = 0; j < 4; ++j)
        o[di][j] *= facj[j];
    // P -> A-frag transpose in-register, then O += P V
#pragma unroll
    for (int kk = 0; kk < 4; ++kk) {
      const int F0 = 2 * kk, F1 = F0 + 1;
      const int srcA = ((2 * g) & 3) * 16 + qy;
      const int srcB = srcA + 16;
      unsigned int a0 = __shfl(wA[F0], srcA), a1 = __shfl(wA[F1], srcA);
      unsigned int b0 = __shfl(wB[F0], srcA), b1 = __shfl(wB[F1], srcA);
      unsigned int c0 = __shfl(wA[F0], srcB), c1 = __shfl(wA[F1], srcB);
      unsigned int e0 = __shfl(wB[F0], srcB), e1 = __shfl(wB[F1], srcB);
      const bool hi = g >= 2;
      union { unsigned int u[4]; bfx8 v; } pu;
      pu.u[0] = hi ? a1 : a0;
      pu.u[1] = hi ? b1 : b0;
      pu.u[2] = hi ? c1 : c0;
      pu.u[3] = hi ? e1 : e0;
      const int pg = kk * 4 + g;
#pragma unroll
      for (int di = 0; di < 4; ++di) {
        int vrow = di * 16 + qy;
        bfx8 vb = *(const bfx8*)&Vs[vrow * 128 + ((pg ^ (vrow & 7)) * 8)];
        o[di] = __builtin_amdgcn_mfma_f32_16x16x32_bf16(pu.v, vb, o[di], 0, 0, 0);
      }
    }
  }
  float lrj[4];
#pragma unroll
  for (int j = 0; j < 4; ++j) lrj[j] = __shfl(lrow, g * 4 + j);
#pragma unroll
  for (int di = 0; di < 4; ++di)
#pragma unroll
    for (int j = 0; j < 4; ++j) {
      int sq_ = q0 + w * 16 + g * 4 + j;
      float v = o[di][j] / lrj[j];
      Ov[(size_t)(b * 2048 + sq_) * 1024 + h * 64 + di * 16 + qy] = f2bf(v);
    }
}

// out = LayerNorm(h + attn_out) * g + b ; one block per row
__global__ __launch_bounds__(256)
void lnk(const float* __restrict__ h, const float* __restrict__ ao,
         const float* __restrict__ g, const float* __restrict__ bb,
         float* __restrict__ out) {
  const int row = blockIdx.x;
  const int tid = threadIdx.x;
  const size_t base = (size_t)row * 1024 + tid * 4;
  fx4 x = *(const fx4*)(h + base);
  fx4 a = *(const fx4*)(ao + base);
  x = x + a;
  float s = x[0] + x[1] + x[2] + x[3];
  float q = x[0] * x[0] + x[1] * x[1] + x[2] * x[2] + x[3] * x[3];
#pragma unroll
  for (int mm = 1; mm < 64; mm <<= 1) {
    s += __shfl_xor(s, mm);
    q += __shfl_xor(q, mm);
  }
  __shared__ float rs[4], rq[4];
  if ((tid & 63) == 0) { rs[tid >> 6] = s; rq[tid >> 6] = q; }
  __syncthreads();
  s = rs[0] + rs[1] + rs[2] + rs[3];
  q = rq[0] + rq[1] + rq[2] + rq[3];
  float mu = s * (1.0f / 1024.0f);
  float var = q * (1.0f / 1024.0f) - mu * mu;
  float rstd = rsqrtf(var + 1e-5f);
  fx4 gg = *(const fx4*)(g + tid * 4);
  fx4 bv = *(const fx4*)(bb + tid * 4);
  fx4 ov;
#pragma unroll
  for (int k = 0; k < 4; ++k) ov[k] = (x[k] - mu) * rstd * gg[k] + bv[k];
  *(fx4*)(out + base) = ov;
}

extern "C" void kernel_launch(void* const* d_in, const int* in_sizes, int n_in,
                              void* d_out, int out_size, void* d_ws, size_t ws_size,
                              hipStream_t stream) {
  const float* h = (const float*)d_in[0];
  const int* msk = (const int*)d_in[1];
  const float* qw = (const float*)d_in[2];
  const float* kw = (const float*)d_in[3];
  const float* vw = (const float*)d_in[4];
  const float* ow = (const float*)d_in[5];
  const float* lng = (const float*)d_in[6];
  const float* lnb = (const float*)d_in[7];
  float* out = (float*)d_out;
  char* ws = (char*)d_ws;

  const size_t MB = 1u << 20;
  unsigned short* h2  = (unsigned short*)(ws + 0 * MB);   // 16 MB [hi|lo]
  unsigned short* w2q = (unsigned short*)(ws + 16 * MB);  // 4 MB
  unsigned short* w2k = (unsigned short*)(ws + 20 * MB);  // 4 MB
  unsigned short* w2v = (unsigned short*)(ws + 24 * MB);  // 4 MB (dead after V gemm)
  unsigned short* Qh  = (unsigned short*)(ws + 24 * MB);  // 8 MB (over w2v, written later)
  unsigned short* Ql  = (unsigned short*)(ws + 32 * MB);  // 8 MB
  unsigned short* Kh  = (unsigned short*)(ws + 40 * MB);  // 8 MB
  unsigned short* Kl  = (unsigned short*)(ws + 48 * MB);  // 8 MB
  unsigned short* Vtb = (unsigned short*)(ws + 56 * MB);  // 8 MB
  unsigned short* Av  = (unsigned short*)(ws + 0 * MB);   // 8 MB (over h2, dead)
  unsigned short* wo  = (unsigned short*)(ws + 8 * MB);   // 2 MB (over h2, dead)
  float* Ao = (float*)(ws + 10 * MB);                     // 16 MB (over h2/w2q/w2k/Qh-head, dead)

  cvtsplit<<<dim3(4096), 256, 0, stream>>>(h, h2);
  cvtsplit<<<dim3(1024), 256, 0, stream>>>(qw, w2q);
  cvtsplit<<<dim3(1024), 256, 0, stream>>>(kw, w2k);
  cvtsplit<<<dim3(1024), 256, 0, stream>>>(vw, w2v);

  // V first (reads w2v, single-term K=1024), then Q/K (3-term; overwrites w2v with Qh)
  gemm_qkv<<<dim3(32, 8), 256, 0, stream>>>(h2, w2q, w2k, w2v, Qh, Ql, Kh, Kl, Vtb, 2, 16);
  gemm_qkv<<<dim3(32, 16), 256, 0, stream>>>(h2, w2q, w2k, w2v, Qh, Ql, Kh, Kl, Vtb, 0, 48);

  attn_fwd<<<dim3(16, 16, 2), 512, 0, stream>>>(Qh, Ql, Kh, Kl, Vtb, msk, Av);

  cvtbf<<<dim3(1024), 256, 0, stream>>>(ow, wo);
  gemm_o<<<dim3(32, 8), 256, 0, stream>>>(Av, wo, Ao);
  lnk<<<dim3(4096), 256, 0, stream>>>(h, Ao, lng, lnb, out);
}

// Round 4
// 160.118 us; speedup vs baseline: 1.7675x; 1.4787x over previous
//
#include <hip/hip_runtime.h>
#include <hip/hip_bf16.h>

typedef __attribute__((ext_vector_type(8))) _Float16 hfx8;
typedef __attribute__((ext_vector_type(4))) float fx4;
typedef __attribute__((ext_vector_type(4))) unsigned short usx4;

#define ATT_SCALE 0.125f

__device__ __forceinline__ unsigned short f2h(float f) {
  union { _Float16 h; unsigned short u; } c;
  c.h = (_Float16)f;
  return c.u;
}

__device__ __forceinline__ unsigned int pkhf(float a, float b) {
  return (unsigned int)f2h(a) | ((unsigned int)f2h(b) << 16);
}

__device__ __forceinline__ void async16(const void* g, void* l) {
  __builtin_amdgcn_global_load_lds(
      (const __attribute__((address_space(1))) void*)g,
      (__attribute__((address_space(3))) void*)l, 16, 0, 0);
}

// f32 -> fp16, 1024 elements per block
__global__ __launch_bounds__(256)
void cvth(const float* __restrict__ s, unsigned short* __restrict__ d) {
  int i = (blockIdx.x * 256 + threadIdx.x) * 4;
  fx4 v = *(const fx4*)(s + i);
  usx4 o;
  o[0] = f2h(v[0]); o[1] = f2h(v[1]); o[2] = f2h(v[2]); o[3] = f2h(v[3]);
  *(usx4*)(d + i) = o;
}

// 4 weight matrices f32 -> fp16; grid.y selects
__global__ __launch_bounds__(256)
void cvtw(const float* __restrict__ s0, const float* __restrict__ s1,
          const float* __restrict__ s2, const float* __restrict__ s3,
          unsigned short* __restrict__ d0, unsigned short* __restrict__ d1,
          unsigned short* __restrict__ d2, unsigned short* __restrict__ d3) {
  const int y = blockIdx.y;
  const float* s = (y == 0) ? s0 : (y == 1) ? s1 : (y == 2) ? s2 : s3;
  unsigned short* d = (y == 0) ? d0 : (y == 1) ? d1 : (y == 2) ? d2 : d3;
  int i = (blockIdx.x * 256 + threadIdx.x) * 4;
  fx4 v = *(const fx4*)(s + i);
  usx4 o;
  o[0] = f2h(v[0]); o[1] = f2h(v[1]); o[2] = f2h(v[2]); o[3] = f2h(v[3]);
  *(usx4*)(d + i) = o;
}

// QKV projection fp16: C[m][n] = sum_k A[m][k]*W[n][k], K=1024.
// grid (32, 24): sel = by>>3 (0=Q flat, 1=K flat, 2=V -> V^T store).
// Double-buffered LDS, prefetch next K-tile before compute.
__global__ __launch_bounds__(256, 2)
void gemm_qkv(const unsigned short* __restrict__ A,
              const unsigned short* __restrict__ Wq,
              const unsigned short* __restrict__ Wk,
              const unsigned short* __restrict__ Wv,
              unsigned short* __restrict__ Qf, unsigned short* __restrict__ Kf,
              unsigned short* __restrict__ Vt) {
  __shared__ unsigned short As[2][128 * 64];
  __shared__ unsigned short Bs[2][128 * 64];
  const int tid = threadIdx.x;
  const int w = tid >> 6, ln = tid & 63;
  const int mt = blockIdx.x;
  const int by = blockIdx.y;
  const int sel = by >> 3;
  const int nt = by & 7;
  const unsigned short* W = (sel == 0) ? Wq : ((sel == 1) ? Wk : Wv);
  const int m0 = mt * 128, n0 = nt * 128;
  const int wr = w >> 1, wc = w & 1;
  fx4 acc[4][4] = {};

  const int lr = ln >> 3;
  const int scg = (ln & 7) ^ lr;
  const unsigned short* Asrc = A + (size_t)(m0 + w * 32 + lr) * 1024 + scg * 8;
  const unsigned short* Bsrc = W + (size_t)(n0 + w * 32 + lr) * 1024 + scg * 8;

#define G_STAGE(KT, BI)                                                        \
  {                                                                            \
    _Pragma("unroll") for (int i = 0; i < 4; ++i) {                            \
      async16(Asrc + (size_t)i * 8 * 1024 + (KT) * 64, &As[BI][(w * 32 + i * 8) * 64]); \
      async16(Bsrc + (size_t)i * 8 * 1024 + (KT) * 64, &Bs[BI][(w * 32 + i * 8) * 64]); \
    }                                                                          \
  }

  G_STAGE(0, 0);
  for (int kt = 0; kt < 16; ++kt) {
    const int cur = kt & 1;
    __syncthreads();
    if (kt < 15) G_STAGE(kt + 1, cur ^ 1);
#pragma unroll
    for (int kk = 0; kk < 2; ++kk) {
      const int kg = kk * 4 + (ln >> 4);
      hfx8 af[4], bfr[4];
#pragma unroll
      for (int mi = 0; mi < 4; ++mi) {
        int row = wr * 64 + mi * 16 + (ln & 15);
        af[mi] = *(const hfx8*)&As[cur][row * 64 + ((kg ^ (row & 7)) * 8)];
      }
#pragma unroll
      for (int ni = 0; ni < 4; ++ni) {
        int row = wc * 64 + ni * 16 + (ln & 15);
        bfr[ni] = *(const hfx8*)&Bs[cur][row * 64 + ((kg ^ (row & 7)) * 8)];
      }
#pragma unroll
      for (int mi = 0; mi < 4; ++mi)
#pragma unroll
        for (int ni = 0; ni < 4; ++ni)
          acc[mi][ni] = __builtin_amdgcn_mfma_f32_16x16x32_f16(af[mi], bfr[ni], acc[mi][ni], 0, 0, 0);
    }
  }
#undef G_STAGE
  const int cb = n0 + wc * 64 + (ln & 15);
  const int rb = m0 + wr * 64 + ((ln >> 4) << 2);
  if (sel < 2) {
    unsigned short* O = sel ? Kf : Qf;
#pragma unroll
    for (int mi = 0; mi < 4; ++mi)
#pragma unroll
      for (int ni = 0; ni < 4; ++ni)
#pragma unroll
        for (int j = 0; j < 4; ++j)
          O[(size_t)(rb + mi * 16 + j) * 1024 + cb + ni * 16] = f2h(acc[mi][ni][j]);
  } else {
    // V^T: Vt[((b*16+h)*64+d)][s], 4 consecutive s per lane -> usx4
#pragma unroll
    for (int mi = 0; mi < 4; ++mi)
#pragma unroll
      for (int ni = 0; ni < 4; ++ni) {
        int s0 = rb + mi * 16;
        int c = cb + ni * 16;
        int bI = s0 >> 11, s = s0 & 2047;
        int hh = c >> 6, dd = c & 63;
        usx4 pk;
#pragma unroll
        for (int j = 0; j < 4; ++j) pk[j] = f2h(acc[mi][ni][j]);
        *(usx4*)&Vt[((size_t)(bI * 16 + hh) * 64 + dd) * 2048 + s] = pk;
      }
  }
}

// O-projection fp16: C = A[4096][1024] * W^T, f32 out; dbuf prefetch
__global__ __launch_bounds__(256, 2)
void gemm_o(const unsigned short* __restrict__ A,
            const unsigned short* __restrict__ W,
            float* __restrict__ O) {
  __shared__ unsigned short As[2][128 * 64];
  __shared__ unsigned short Bs[2][128 * 64];
  const int tid = threadIdx.x;
  const int w = tid >> 6, ln = tid & 63;
  const int mt = blockIdx.x, nt = blockIdx.y;
  const int m0 = mt * 128, n0 = nt * 128;
  const int wr = w >> 1, wc = w & 1;
  fx4 acc[4][4] = {};
  const int lr = ln >> 3;
  const int scg = (ln & 7) ^ lr;
  const unsigned short* Asrc = A + (size_t)(m0 + w * 32 + lr) * 1024 + scg * 8;
  const unsigned short* Bsrc = W + (size_t)(n0 + w * 32 + lr) * 1024 + scg * 8;

#define G_STAGE(KT, BI)                                                        \
  {                                                                            \
    _Pragma("unroll") for (int i = 0; i < 4; ++i) {                            \
      async16(Asrc + (size_t)i * 8 * 1024 + (KT) * 64, &As[BI][(w * 32 + i * 8) * 64]); \
      async16(Bsrc + (size_t)i * 8 * 1024 + (KT) * 64, &Bs[BI][(w * 32 + i * 8) * 64]); \
    }                                                                          \
  }

  G_STAGE(0, 0);
  for (int kt = 0; kt < 16; ++kt) {
    const int cur = kt & 1;
    __syncthreads();
    if (kt < 15) G_STAGE(kt + 1, cur ^ 1);
#pragma unroll
    for (int kk = 0; kk < 2; ++kk) {
      const int kg = kk * 4 + (ln >> 4);
      hfx8 af[4], bfr[4];
#pragma unroll
      for (int mi = 0; mi < 4; ++mi) {
        int row = wr * 64 + mi * 16 + (ln & 15);
        af[mi] = *(const hfx8*)&As[cur][row * 64 + ((kg ^ (row & 7)) * 8)];
      }
#pragma unroll
      for (int ni = 0; ni < 4; ++ni) {
        int row = wc * 64 + ni * 16 + (ln & 15);
        bfr[ni] = *(const hfx8*)&Bs[cur][row * 64 + ((kg ^ (row & 7)) * 8)];
      }
#pragma unroll
      for (int mi = 0; mi < 4; ++mi)
#pragma unroll
        for (int ni = 0; ni < 4; ++ni)
          acc[mi][ni] = __builtin_amdgcn_mfma_f32_16x16x32_f16(af[mi], bfr[ni], acc[mi][ni], 0, 0, 0);
    }
  }
#undef G_STAGE
  const int cb = n0 + wc * 64 + (ln & 15);
  const int rb = m0 + wr * 64 + ((ln >> 4) << 2);
#pragma unroll
  for (int mi = 0; mi < 4; ++mi)
#pragma unroll
    for (int ni = 0; ni < 4; ++ni)
#pragma unroll
      for (int j = 0; j < 4; ++j)
        O[(size_t)(rb + mi * 16 + j) * 1024 + cb + ni * 16] = acc[mi][ni][j];
}

// Flash attention fp16, swapped QK^T; double-buffered K/V; mask preloaded.
// block = (qt,h,b); 8 waves x 16 q-rows = 128 q-rows; K-tile = 128.
__global__ __launch_bounds__(512, 4)
void attn_fwd(const unsigned short* __restrict__ Qf,
              const unsigned short* __restrict__ Kf,
              const unsigned short* __restrict__ Vt,
              const int* __restrict__ mask,
              unsigned short* __restrict__ Ov) {
  __shared__ unsigned short Ks[2][128 * 64];
  __shared__ unsigned short Vs[2][64 * 128];
  __shared__ float mfAll[2048];
  const int tid = threadIdx.x;
  const int w = tid >> 6, ln = tid & 63;
  const int qt = blockIdx.x, h = blockIdx.y, b = blockIdx.z;
  const int q0 = qt * 128;
  const int g = ln >> 4, qy = ln & 15;

  // Q as B-fragment: lane holds Q[q0 + w*16 + qy][dims kk*32 + g*8 + 0..7]
  hfx8 qf[2];
  {
    int q = q0 + w * 16 + qy;
    size_t off = (size_t)(b * 2048 + q) * 1024 + h * 64 + g * 8;
    qf[0] = *(const hfx8*)(Qf + off);
    qf[1] = *(const hfx8*)(Qf + off + 32);
  }
  fx4 o[4] = {};
  float mrow = -INFINITY, lrow = 0.f;

  const int lr = ln >> 3;
  const int scg = (ln & 7) ^ lr;
  const unsigned short* Ksrc = Kf + (size_t)(b * 2048 + w * 16 + lr) * 1024 + h * 64 + scg * 8;
  const unsigned short* Vbase = Vt + (size_t)(b * 16 + h) * 64 * 2048;

  // preload mask -> additive floats (once per block)
  {
    int i4 = tid * 4;
    const int* mp = mask + b * 2048 + i4;
#pragma unroll
    for (int j = 0; j < 4; ++j)
      mfAll[i4 + j] = (mp[j] == 0) ? -1e30f : 0.0f;
  }

#define A_STAGE(KT, BI)                                                        \
  {                                                                            \
    _Pragma("unroll") for (int i = 0; i < 2; ++i)                              \
        async16(Ksrc + (size_t)((KT) * 128 + i * 8) * 1024,                    \
                &Ks[BI][(w * 16 + i * 8) * 64]);                               \
    _Pragma("unroll") for (int i = 0; i < 2; ++i) {                            \
      int d = w * 8 + i * 4 + g;                                               \
      async16(Vbase + (size_t)d * 2048 + (KT) * 128 + ((qy ^ (d & 7)) * 8),    \
              &Vs[BI][(w * 8 + i * 4) * 128]);                                 \
    }                                                                          \
  }

  A_STAGE(0, 0);
  for (int kt = 0; kt < 16; ++kt) {
    const int cur = kt & 1;
    __syncthreads();
    if (kt < 15) A_STAGE(kt + 1, cur ^ 1);

    // S^T = K Q^T: C[key = ni*16 + g*4 + j][q = qy]
    fx4 s[8];
#pragma unroll
    for (int ni = 0; ni < 8; ++ni) {
      fx4 z = {};
#pragma unroll
      for (int kk = 0; kk < 2; ++kk) {
        int row = ni * 16 + qy;
        int kg = kk * 4 + g;
        hfx8 kf = *(const hfx8*)&Ks[cur][row * 64 + ((kg ^ (row & 7)) * 8)];
        z = __builtin_amdgcn_mfma_f32_16x16x32_f16(kf, qf[kk], z, 0, 0, 0);
      }
      s[ni] = z;
    }
    // scale + mask + per-q (lane-local) online softmax
    float tm = -INFINITY;
#pragma unroll
    for (int ni = 0; ni < 8; ++ni) {
      fx4 mfv = *(const fx4*)&mfAll[kt * 128 + ni * 16 + g * 4];
#pragma unroll
      for (int j = 0; j < 4; ++j) {
        float v = s[ni][j] * ATT_SCALE + mfv[j];
        s[ni][j] = v;
        tm = fmaxf(tm, v);
      }
    }
    tm = fmaxf(tm, __shfl_xor(tm, 16));
    tm = fmaxf(tm, __shfl_xor(tm, 32));
    float mn = fmaxf(mrow, tm);
    float fac = __expf(mrow - mn);
    mrow = mn;
    float psum = 0.f;
    unsigned int wA[8], wB[8];
#pragma unroll
    for (int ni = 0; ni < 8; ++ni) {
      float p0 = __expf(s[ni][0] - mrow);
      float p1 = __expf(s[ni][1] - mrow);
      float p2 = __expf(s[ni][2] - mrow);
      float p3 = __expf(s[ni][3] - mrow);
      psum += (p0 + p1) + (p2 + p3);
      wA[ni] = pkhf(p0, p1);
      wB[ni] = pkhf(p2, p3);
    }
    psum += __shfl_xor(psum, 16);
    psum += __shfl_xor(psum, 32);
    lrow = lrow * fac + psum;
    // rescale o (o rows are q = g*4 + j; fac lives at lane q)
    float facj[4];
#pragma unroll
    for (int j = 0; j < 4; ++j) facj[j] = __shfl(fac, g * 4 + j);
#pragma unroll
    for (int di = 0; di < 4; ++di)
#pragma unroll
      for (int j = 0; j < 4; ++j)
        o[di][j] *= facj[j];
    // P -> A-frag transpose in-register, then O += P V
#pragma unroll
    for (int kk = 0; kk < 4; ++kk) {
      const int F0 = 2 * kk, F1 = F0 + 1;
      const int srcA = ((2 * g) & 3) * 16 + qy;
      const int srcB = srcA + 16;
      unsigned int a0 = __shfl(wA[F0], srcA), a1 = __shfl(wA[F1], srcA);
      unsigned int b0 = __shfl(wB[F0], srcA), b1 = __shfl(wB[F1], srcA);
      unsigned int c0 = __shfl(wA[F0], srcB), c1 = __shfl(wA[F1], srcB);
      unsigned int e0 = __shfl(wB[F0], srcB), e1 = __shfl(wB[F1], srcB);
      const bool hi = g >= 2;
      union { unsigned int u[4]; hfx8 v; } pu;
      pu.u[0] = hi ? a1 : a0;
      pu.u[1] = hi ? b1 : b0;
      pu.u[2] = hi ? c1 : c0;
      pu.u[3] = hi ? e1 : e0;
      const int pg = kk * 4 + g;
#pragma unroll
      for (int di = 0; di < 4; ++di) {
        int vrow = di * 16 + qy;
        hfx8 vb = *(const hfx8*)&Vs[cur][vrow * 128 + ((pg ^ (vrow & 7)) * 8)];
        o[di] = __builtin_amdgcn_mfma_f32_16x16x32_f16(pu.v, vb, o[di], 0, 0, 0);
      }
    }
  }
#undef A_STAGE
  float lrj[4];
#pragma unroll
  for (int j = 0; j < 4; ++j) lrj[j] = __shfl(lrow, g * 4 + j);
#pragma unroll
  for (int di = 0; di < 4; ++di)
#pragma unroll
    for (int j = 0; j < 4; ++j) {
      int sq_ = q0 + w * 16 + g * 4 + j;
      float v = o[di][j] / lrj[j];
      Ov[(size_t)(b * 2048 + sq_) * 1024 + h * 64 + di * 16 + qy] = f2h(v);
    }
}

// out = LayerNorm(h + attn_out) * g + b ; one block per row
__global__ __launch_bounds__(256)
void lnk(const float* __restrict__ h, const float* __restrict__ ao,
         const float* __restrict__ g, const float* __restrict__ bb,
         float* __restrict__ out) {
  const int row = blockIdx.x;
  const int tid = threadIdx.x;
  const size_t base = (size_t)row * 1024 + tid * 4;
  fx4 x = *(const fx4*)(h + base);
  fx4 a = *(const fx4*)(ao + base);
  x = x + a;
  float s = x[0] + x[1] + x[2] + x[3];
  float q = x[0] * x[0] + x[1] * x[1] + x[2] * x[2] + x[3] * x[3];
#pragma unroll
  for (int mm = 1; mm < 64; mm <<= 1) {
    s += __shfl_xor(s, mm);
    q += __shfl_xor(q, mm);
  }
  __shared__ float rs[4], rq[4];
  if ((tid & 63) == 0) { rs[tid >> 6] = s; rq[tid >> 6] = q; }
  __syncthreads();
  s = rs[0] + rs[1] + rs[2] + rs[3];
  q = rq[0] + rq[1] + rq[2] + rq[3];
  float mu = s * (1.0f / 1024.0f);
  float var = q * (1.0f / 1024.0f) - mu * mu;
  float rstd = rsqrtf(var + 1e-5f);
  fx4 gg = *(const fx4*)(g + tid * 4);
  fx4 bv = *(const fx4*)(bb + tid * 4);
  fx4 ov;
#pragma unroll
  for (int k = 0; k < 4; ++k) ov[k] = (x[k] - mu) * rstd * gg[k] + bv[k];
  *(fx4*)(out + base) = ov;
}

extern "C" void kernel_launch(void* const* d_in, const int* in_sizes, int n_in,
                              void* d_out, int out_size, void* d_ws, size_t ws_size,
                              hipStream_t stream) {
  const float* h = (const float*)d_in[0];
  const int* msk = (const int*)d_in[1];
  const float* qw = (const float*)d_in[2];
  const float* kw = (const float*)d_in[3];
  const float* vw = (const float*)d_in[4];
  const float* ow = (const float*)d_in[5];
  const float* lng = (const float*)d_in[6];
  const float* lnb = (const float*)d_in[7];
  float* out = (float*)d_out;
  char* ws = (char*)d_ws;

  const size_t MB = 1u << 20;
  unsigned short* h16 = (unsigned short*)(ws + 0 * MB);   // 8 MB
  unsigned short* w16q = (unsigned short*)(ws + 8 * MB);  // 2 MB
  unsigned short* w16k = (unsigned short*)(ws + 10 * MB); // 2 MB
  unsigned short* w16v = (unsigned short*)(ws + 12 * MB); // 2 MB
  unsigned short* w16o = (unsigned short*)(ws + 14 * MB); // 2 MB
  unsigned short* Qf  = (unsigned short*)(ws + 16 * MB);  // 8 MB
  unsigned short* Kf  = (unsigned short*)(ws + 24 * MB);  // 8 MB
  unsigned short* Vtb = (unsigned short*)(ws + 32 * MB);  // 8 MB
  unsigned short* Av  = (unsigned short*)(ws + 40 * MB);  // 8 MB
  float* Ao = (float*)(ws + 48 * MB);                     // 16 MB

  cvth<<<dim3(4096), 256, 0, stream>>>(h, h16);
  cvtw<<<dim3(1024, 4), 256, 0, stream>>>(qw, kw, vw, ow, w16q, w16k, w16v, w16o);

  gemm_qkv<<<dim3(32, 24), 256, 0, stream>>>(h16, w16q, w16k, w16v, Qf, Kf, Vtb);
  attn_fwd<<<dim3(16, 16, 2), 512, 0, stream>>>(Qf, Kf, Vtb, msk, Av);
  gemm_o<<<dim3(32, 8), 256, 0, stream>>>(Av, w16o, Ao);
  lnk<<<dim3(4096), 256, 0, stream>>>(h, Ao, lng, lnb, out);
}